// Round 5
// baseline (253.737 us; speedup 1.0000x reference)
//
#include <hip/hip_runtime.h>
#include <math.h>

// ---- static config (mirror of reference) ----
#define GNUM 4
#define NG 512
#define NN 2048
#define EE 32768
#define HC 128
#define HEADS 4
#define HID 32
#define GRID_PTS 500
#define QN 20
#define ODIM 32
#define MAXE 160              // per-dst edge cap (deg ~ Poisson(16); P(>159) ~ 0)

#define LOG2E 1.44269504088896340736f
#define NEG_HALF_LOG2E -0.72134752044448170368f
#define N_POW_M02 0.2871745887492588f   // 512^-0.2
#define SIG_K 144.269504089f            // 100 * log2(e)

typedef float v2f __attribute__((ext_vector_type(2)));

__device__ __forceinline__ float fexp2(float x){ return __builtin_amdgcn_exp2f(x); }
__device__ __forceinline__ float frcp(float x){ return __builtin_amdgcn_rcpf(x); }

struct SmemKDE {
  __align__(16) float2 xs[NG];   // (x, x^2) 4KB — PLANE=0 (layer-0) staging
  float4 wred4[8];
  float sc[4];
  float wsum[8], woff[9];
  float redw[QN][8], redg[QN][8];
  float qs[QN];
};
struct SmemXW  { float rows[4][HC]; int cnt[4]; };
struct SmemGat {
  int   ssrc[4][MAXE];
  float sexp[4][MAXE][HEADS];
};
struct SmemFin { float sdm[384]; };
union Smem { SmemKDE kde; SmemXW xw; SmemGat gat; SmemFin fin; };

// ---------------- KDE readout phase (one (g,d) per task b; b in [0,512)) ----------------
// PLANE=1: sample data in two planes vpl/spl [channel][node] (v and v^2); global uniform float4
//          loads + pk_fma polynomial.
// PLANE=0: xsrc is [node][channel] (layer-0 x); strided per-thread load staged to LDS (v,v^2).
// Both paths compute exponent as fma(kk, v2, fma(c1, v, c0)) in ascending sample order →
// bit-identical across paths. Partials dense (no atomics/zero-init): [d][g*32+o].
template<int PLANE>
__device__ void kde_phase(Smem& sm, const float* __restrict__ vpl, const float* __restrict__ spl,
        const float* __restrict__ xsrc, int b,
        const float* __restrict__ kW, const float* __restrict__ kb, float* __restrict__ kacc,
        const float* __restrict__ lpW, const float* __restrict__ lpb,
        const float* __restrict__ poolw, float* __restrict__ macc){
  int g = b >> 7, d = b & 127;
  int t = threadIdx.x;
  int lane = t & 63, wave = t >> 6;
  size_t base = (size_t)d*NN + g*NG;
  float v, v2;
  if (PLANE){
    v  = vpl[base + t];
    v2 = spl[base + t];
  } else {
    v = xsrc[((size_t)g*NG + t)*HC + d];
    v2 = v*v;
    sm.kde.xs[t] = make_float2(v, v2);
  }
  float mn=v, mx=v, smv=v, sq=v2;
  #pragma unroll
  for (int m=32; m>0; m>>=1){
    mn = fminf(mn, __shfl_xor(mn, m, 64));
    mx = fmaxf(mx, __shfl_xor(mx, m, 64));
    smv += __shfl_xor(smv, m, 64);
    sq += __shfl_xor(sq, m, 64);
  }
  if (lane==0) sm.kde.wred4[wave] = make_float4(mn,mx,smv,sq);
  __syncthreads();
  if (t==0){
    float4 r = sm.kde.wred4[0];
    #pragma unroll
    for (int i=1;i<8;++i){
      float4 bb = sm.kde.wred4[i];
      r.x = fminf(r.x,bb.x); r.y = fmaxf(r.y,bb.y); r.z += bb.z; r.w += bb.w;
    }
    float mean = r.z * (1.f/NG);
    float var  = fmaxf(r.w*(1.f/NG) - mean*mean, 0.f);
    float sd   = sqrtf(var) + (1e-8f/3.f);
    float h    = 1.06f * sd * N_POW_M02;
    float lo = r.x - 1e-6f, hi = r.y + 1e-6f;
    sm.kde.sc[0] = lo;
    sm.kde.sc[1] = (hi-lo)*(1.f/(GRID_PTS-1));
    sm.kde.sc[2] = NEG_HALF_LOG2E/(h*h);
    sm.kde.sc[3] = poolw[0]*mean + poolw[1]*r.y;
  }
  __syncthreads();
  float lo = sm.kde.sc[0], st = sm.kde.sc[1], kk = sm.kde.sc[2];
  float gv = lo + st*(float)t;
  float acc = 0.f;
  if (PLANE){
    float c0 = kk*gv*gv, c1 = -2.f*kk*gv;
    v2f c0v = {c0, c0}, c1v = {c1, c1}, kkv = {kk, kk};
    const float4* pv = (const float4*)(vpl + base);
    const float4* ps = (const float4*)(spl + base);
    #pragma unroll 8
    for (int i=0;i<NG/4;++i){
      float4 a = pv[i];      // x0..x3   — uniform addr: 1 request/wave
      float4 bq = ps[i];     // x0^2..x3^2
      v2f alo = {a.x, a.y}, ahi = {a.z, a.w};
      v2f blo = {bq.x, bq.y}, bhi = {bq.z, bq.w};
      v2f plo = __builtin_elementwise_fma(kkv, blo, __builtin_elementwise_fma(c1v, alo, c0v));
      v2f phi = __builtin_elementwise_fma(kkv, bhi, __builtin_elementwise_fma(c1v, ahi, c0v));
      acc += fexp2(plo.x);
      acc += fexp2(plo.y);
      acc += fexp2(phi.x);
      acc += fexp2(phi.y);
    }
  } else {
    float c0 = kk*gv*gv, c1 = -2.f*kk*gv;
    const float4* p4 = (const float4*)sm.kde.xs;
    #pragma unroll 8
    for (int i=0;i<NG/2;++i){
      float4 s2 = p4[i];     // (x0, x0^2, x1, x1^2)
      acc += fexp2(fmaf(kk, s2.y, fmaf(c1, s2.x, c0)));
      acc += fexp2(fmaf(kk, s2.w, fmaf(c1, s2.z, c0)));
    }
  }
  if (t >= GRID_PTS) acc = 0.f;   // mask lanes beyond the grid (kept out of hot loop)
  // inclusive scan
  float sv = acc;
  #pragma unroll
  for (int off=1; off<64; off<<=1){
    float n = __shfl_up(sv, off, 64);
    if (lane >= off) sv += n;
  }
  if (lane==63) sm.kde.wsum[wave] = sv;
  __syncthreads();
  if (t==0){
    float r2 = 0.f;
    #pragma unroll
    for (int i=0;i<8;++i){ sm.kde.woff[i]=r2; r2+=sm.kde.wsum[i]; }
    sm.kde.woff[8]=r2;
  }
  if (t < QN*8){ ((float*)sm.kde.redw)[t]=0.f; ((float*)sm.kde.redg)[t]=0.f; }
  __syncthreads();
  float invt = 1.f/fmaxf(sm.kde.woff[8], 1e-8f);
  float c = (sv + sm.kde.woff[wave]) * invt;
  float cw0 = __shfl(c, 0, 64), cw1 = __shfl(c, 63, 64);
  int qlo = max(0, (int)ceilf((cw0 - 0.17f)*(float)(QN-1)));
  int qhi = min(QN-1, (int)floorf((cw1 + 0.17f)*(float)(QN-1)));
  for (int q=qlo; q<=qhi; ++q){
    float w = 0.f;
    if (t < GRID_PTS){
      float dist = fabsf(c - (float)q*(1.f/(QN-1)));
      w = frcp(1.f + fexp2(SIG_K*dist));
    }
    float gw = gv*w;
    #pragma unroll
    for (int m=32;m>0;m>>=1){
      w  += __shfl_xor(w,  m, 64);
      gw += __shfl_xor(gw, m, 64);
    }
    if (lane==0){ sm.kde.redw[q][wave]=w; sm.kde.redg[q][wave]=gw; }
  }
  __syncthreads();
  if (t < QN){
    float sw=0.f, sgw=0.f;
    #pragma unroll
    for (int i=0;i<8;++i){ sw+=sm.kde.redw[t][i]; sgw+=sm.kde.redg[t][i]; }
    sm.kde.qs[t] = sgw / (sw + 1e-8f);
  }
  __syncthreads();
  if (t < ODIM){
    float a = 0.f;
    const float* kwb = kW + (size_t)d*QN*ODIM + t;
    #pragma unroll
    for (int q=0;q<QN;++q) a += sm.kde.qs[q]*kwb[q*ODIM];
    if (d==0) a += kb[t];
    kacc[(size_t)d*128 + g*ODIM + t] = a;           // dense partial, written exactly once
    float bb = sm.kde.sc[3]*lpW[d*ODIM + t];
    if (d==0) bb += lpb[t];
    macc[(size_t)d*128 + g*ODIM + t] = bb;
  }
  __syncthreads();
}

// ---------------- gather core (4 dst/block; returns this thread's channel value) ----------------
__device__ float gather_core(Smem& sm, int d, int sub, int tl,
        const int* __restrict__ csr, const int* __restrict__ deg,
        const float* __restrict__ als, const float* __restrict__ ald,
        const float* __restrict__ xh, const float* __restrict__ bias){
  int dg = deg[d];                       // already clamped to MAXE-1 at build time
  int E = dg + 1;                        // + self loop
  int Ep = (E + 7) & ~7;                 // padded length (pads contribute exactly 0)
  const int* base = csr + d*MAXE;
  float a0 = ald[d*4+0], a1 = ald[d*4+1], a2 = ald[d*4+2], a3 = ald[d*4+3];
  for (int i=tl; i<Ep; i+=128){
    int s = (i < dg) ? base[i] : d;
    sm.gat.ssrc[sub][i] = s;
    if (i < E){
      float4 av = *(const float4*)(als + (size_t)s*4);   // one 16B load
      float e0 = av.x+a0, e1 = av.y+a1, e2 = av.z+a2, e3 = av.w+a3;
      e0 = (e0>=0.f)? e0 : 0.2f*e0;
      e1 = (e1>=0.f)? e1 : 0.2f*e1;
      e2 = (e2>=0.f)? e2 : 0.2f*e2;
      e3 = (e3>=0.f)? e3 : 0.2f*e3;
      sm.gat.sexp[sub][i][0]=e0; sm.gat.sexp[sub][i][1]=e1;
      sm.gat.sexp[sub][i][2]=e2; sm.gat.sexp[sub][i][3]=e3;
    } else {
      sm.gat.sexp[sub][i][0]=0.f; sm.gat.sexp[sub][i][1]=0.f;
      sm.gat.sexp[sub][i][2]=0.f; sm.gat.sexp[sub][i][3]=0.f;
    }
  }
  __syncthreads();
  int h = tl >> 5, l32 = tl & 31;
  float mx = -INFINITY;
  for (int i=l32; i<E; i+=32) mx = fmaxf(mx, sm.gat.sexp[sub][i][h]);
  #pragma unroll
  for (int m=16; m>0; m>>=1) mx = fmaxf(mx, __shfl_xor(mx, m, 32));
  float sdn = 0.f;
  for (int i=l32; i<E; i+=32){
    float ev = fexp2(LOG2E*(sm.gat.sexp[sub][i][h] - mx));
    sm.gat.sexp[sub][i][h] = ev;         // head-local: written & read by the same 32-lane group
    sdn += ev;
  }
  #pragma unroll
  for (int m=16; m>0; m>>=1) sdn += __shfl_xor(sdn, m, 32);
  float fac = 1.f/(sdn + 1e-16f);
  float acc = bias[tl];
  for (int i0=0; i0<Ep; i0+=8){
    #pragma unroll
    for (int k=0;k<8;++k){
      int i = i0 + k;
      acc += sm.gat.sexp[sub][i][h]*fac * xh[(size_t)sm.gat.ssrc[sub][i]*HC + tl];
    }
  }
  __syncthreads();                        // gat LDS free for reuse after this
  return acc;
}

// ---------------- xw helper: GEMV row (in LDS rows[sub]) -> xh + logits ----------------
__device__ void xw_emit(Smem& sm, int sub, int j, int n,
        const float* __restrict__ W, const float* __restrict__ as_, const float* __restrict__ ad_,
        float* __restrict__ xh, float* __restrict__ als, float* __restrict__ ald){
  float acc = 0.f;
  #pragma unroll 8
  for (int c2=0;c2<HC;++c2)
    acc += sm.xw.rows[sub][c2]*W[(size_t)c2*HC + j];
  xh[(size_t)n*HC + j] = acc;
  int h = j >> 5, cc = j & 31;
  float ps = acc*as_[h*HID+cc], pd = acc*ad_[h*HID+cc];
  #pragma unroll
  for (int m=16;m>0;m>>=1){
    ps += __shfl_xor(ps, m, 32);
    pd += __shfl_xor(pd, m, 32);
  }
  if (cc==0){ als[n*HEADS+h]=ps; ald[n*HEADS+h]=pd; }
}

// ---------------- transpose write: rows[4][128] -> (v-plane, v^2-plane) ----------------
__device__ void write_transposed(Smem& sm, int t, int n0,
                                 float* __restrict__ vpl, float* __restrict__ spl){
  if (t < HC){
    float v0 = sm.xw.rows[0][t], v1 = sm.xw.rows[1][t];
    float v2 = sm.xw.rows[2][t], v3 = sm.xw.rows[3][t];
    *(float4*)(vpl + (size_t)t*NN + n0) = make_float4(v0, v1, v2, v3);
    *(float4*)(spl + (size_t)t*NN + n0) = make_float4(v0*v0, v1*v1, v2*v2, v3*v3);
  }
}

// ================= L0: kde0(x direct, bids 0..511) | xw0(x)+CSR (bids 512..1023) =========
__global__ __launch_bounds__(512) void k_L0(const float* __restrict__ x,
        const float* __restrict__ kW, const float* __restrict__ kb, float* __restrict__ kacc,
        const float* __restrict__ lpW, const float* __restrict__ lpb,
        const float* __restrict__ poolw, float* __restrict__ macc,
        const float* __restrict__ W, const float* __restrict__ as_, const float* __restrict__ ad_,
        float* __restrict__ xh, float* __restrict__ als, float* __restrict__ ald,
        const int* __restrict__ src, const int* __restrict__ dst,
        int* __restrict__ deg, int* __restrict__ csr, int* __restrict__ donecnt){
  __shared__ Smem sm;
  int t = threadIdx.x;
  if (blockIdx.x < 512){
    kde_phase<0>(sm, nullptr, nullptr, x, blockIdx.x, kW, kb, kacc, lpW, lpb, poolw, macc);
  } else {
    int b2 = blockIdx.x - 512;
    if (b2 == 0 && t == 0) *donecnt = 0;   // re-init for k_L2's last-block pattern
    int sub = t >> 7, j = t & 127;
    int n = b2*4 + sub;
    if (t < 4) sm.xw.cnt[t] = 0;
    sm.xw.rows[sub][j] = x[(size_t)n*HC + j];
    __syncthreads();
    // CSR build: this block owns dst nodes [4*b2, 4*b2+4); scan all edges (L2-resident)
    int base4 = b2*4;
    for (int e = t; e < EE; e += 512){
      int dd = dst[e];
      unsigned r = (unsigned)(dd - base4);
      if (r < 4u){
        int p = atomicAdd(&sm.xw.cnt[r], 1);
        if (p < MAXE) csr[dd*MAXE + p] = src[e];
      }
    }
    xw_emit(sm, sub, j, n, W, as_, ad_, xh, als, ald);
    __syncthreads();
    if (t < 4) deg[base4 + t] = min(sm.xw.cnt[t], MAXE-1);
  }
}

// ================= G0: gather0 -> cur1 planes (post-relu) + fused xw1 =================
__global__ __launch_bounds__(512) void k_G0(const int* __restrict__ csr, const int* __restrict__ deg,
        const float* __restrict__ als_in, const float* __restrict__ ald_in,
        const float* __restrict__ xh_in, const float* __restrict__ bias,
        float* __restrict__ c1v, float* __restrict__ c1s,
        const float* __restrict__ W1, const float* __restrict__ as1, const float* __restrict__ ad1,
        float* __restrict__ xh2, float* __restrict__ als2, float* __restrict__ ald2){
  __shared__ Smem sm;
  int t = threadIdx.x;
  int sub = t >> 7, tl = t & 127;
  int d = blockIdx.x*4 + sub;
  float acc = gather_core(sm, d, sub, tl, csr, deg, als_in, ald_in, xh_in, bias);
  sm.xw.rows[sub][tl] = fmaxf(acc, 0.f);   // post-relu: input to both kde1 and xw1
  __syncthreads();
  write_transposed(sm, t, blockIdx.x*4, c1v, c1s);
  xw_emit(sm, sub, tl, d, W1, as1, ad1, xh2, als2, ald2);
}

// ================= L1: kde1 (bids 0..511) | gather1 -> cur2 planes (bids 512..1023) =======
__global__ __launch_bounds__(512) void k_L1(const float* __restrict__ c1v, const float* __restrict__ c1s,
        const float* __restrict__ kW, const float* __restrict__ kb, float* __restrict__ kacc,
        const float* __restrict__ lpW, const float* __restrict__ lpb,
        const float* __restrict__ poolw, float* __restrict__ macc,
        const int* __restrict__ csr, const int* __restrict__ deg,
        const float* __restrict__ als2, const float* __restrict__ ald2,
        const float* __restrict__ xh2, const float* __restrict__ bias,
        float* __restrict__ c2v, float* __restrict__ c2s){
  __shared__ Smem sm;
  int t = threadIdx.x;
  if (blockIdx.x < 512){
    kde_phase<1>(sm, c1v, c1s, nullptr, blockIdx.x, kW, kb, kacc, lpW, lpb, poolw, macc);
  } else {
    int b2 = blockIdx.x - 512;
    int sub = t >> 7, tl = t & 127;
    int d = b2*4 + sub;
    float acc = gather_core(sm, d, sub, tl, csr, deg, als2, ald2, xh2, bias);
    sm.xw.rows[sub][tl] = acc;             // no relu on last layer
    __syncthreads();
    write_transposed(sm, t, b2*4, c2v, c2s);
  }
}

// ================= L2: kde2 + last-block final reduction =================
__global__ __launch_bounds__(512) void k_L2(const float* __restrict__ c2v, const float* __restrict__ c2s,
        const float* __restrict__ kW, const float* __restrict__ kb, float* __restrict__ kacc,
        const float* __restrict__ lpW, const float* __restrict__ lpb,
        const float* __restrict__ poolw, float* __restrict__ macc,
        const float* __restrict__ mpart, const float* __restrict__ kpart,
        const float* __restrict__ beta, const float* __restrict__ h0,
        float* __restrict__ out, int* __restrict__ donecnt){
  __shared__ Smem sm;
  __shared__ int lastFlag;
  int t = threadIdx.x;
  kde_phase<1>(sm, c2v, c2s, nullptr, blockIdx.x, kW, kb, kacc, lpW, lpb, poolw, macc);
  __threadfence();                         // make this block's partials device-visible
  if (t == 0) lastFlag = (atomicAdd(donecnt, 1) == 511);
  __syncthreads();
  if (!lastFlag) return;
  __threadfence();                         // acquire side: see all blocks' partials
  if (t < 384){
    int l = t >> 7, tt = t & 127;
    const float* mrow = mpart + (size_t)l*16384 + tt;
    const float* krow = kpart + (size_t)l*16384 + tt;
    float s = 0.f;
    #pragma unroll 8
    for (int d2=0; d2<128; ++d2) s += mrow[(size_t)d2*128] + krow[(size_t)d2*128];
    sm.fin.sdm[t] = s;
  }
  __syncthreads();
  if (t < 128){
    int g = t >> 5, o = t & 31;
    float s3 = (sm.fin.sdm[t] + sm.fin.sdm[t+128] + sm.fin.sdm[t+256]) * (1.f/3.f) * beta[o];
    #pragma unroll
    for (int m=16; m>0; m>>=1) s3 += __shfl_xor(s3, m, 32);
    if (o == 0) out[g] = s3 + h0[0];
  }
}

extern "C" void kernel_launch(void* const* d_in, const int* in_sizes, int n_in,
                              void* d_out, int out_size, void* d_ws, size_t ws_size,
                              hipStream_t stream) {
  (void)in_sizes; (void)n_in; (void)out_size; (void)ws_size;
  const float* x    = (const float*)d_in[0];
  const int*   ei   = (const int*)d_in[1];
  const int*   srcp = ei;
  const int*   dstp = ei + EE;
  const float* W[2]   = {(const float*)d_in[3], (const float*)d_in[7]};
  const float* As[2]  = {(const float*)d_in[4], (const float*)d_in[8]};
  const float* Ad[2]  = {(const float*)d_in[5], (const float*)d_in[9]};
  const float* Bi[2]  = {(const float*)d_in[6], (const float*)d_in[10]};
  const float* lpW[3] = {(const float*)d_in[11], (const float*)d_in[13], (const float*)d_in[15]};
  const float* lpb[3] = {(const float*)d_in[12], (const float*)d_in[14], (const float*)d_in[16]};
  const float* kW[3]  = {(const float*)d_in[17], (const float*)d_in[19], (const float*)d_in[21]};
  const float* kb[3]  = {(const float*)d_in[18], (const float*)d_in[20], (const float*)d_in[22]};
  const float* poolw  = (const float*)d_in[23];
  const float* beta   = (const float*)d_in[24];
  const float* h0     = (const float*)d_in[25];
  float* out = (float*)d_out;

  // workspace layout (floats unless noted); cur planes are [128][2048]
  float* ws = (float*)d_ws;
  float* c1v   = ws;                   // 262144
  float* c1s   = c1v + 262144;         // 262144
  float* c2v   = c1s + 262144;         // 262144
  float* c2s   = c2v + 262144;         // 262144
  float* xh    = c2s + 262144;         // 262144 (layer 0)
  float* xh2   = xh + 262144;          // 262144 (layer 1)
  float* als   = xh2 + 262144;         // 8192
  float* ald   = als + 8192;           // 8192
  float* als2  = ald + 8192;           // 8192
  float* ald2  = als2 + 8192;          // 8192
  float* mpart = ald2 + 8192;          // 3*128*128 = 49152 (dense, no init needed)
  float* kpart = mpart + 49152;        // 49152
  int*   deg   = (int*)(kpart + 49152);// 2048
  int*   csr   = deg + 2048;           // 2048*160
  int*   donecnt = csr + 2048*MAXE;    // 1

  k_L0<<<1024, 512, 0, stream>>>(x, kW[0], kb[0], kpart, lpW[0], lpb[0], poolw, mpart,
                                 W[0], As[0], Ad[0], xh, als, ald,
                                 srcp, dstp, deg, csr, donecnt);
  k_G0<<<512, 512, 0, stream>>>(csr, deg, als, ald, xh, Bi[0], c1v, c1s,
                                W[1], As[1], Ad[1], xh2, als2, ald2);
  k_L1<<<1024, 512, 0, stream>>>(c1v, c1s, kW[1], kb[1], kpart+16384, lpW[1], lpb[1], poolw, mpart+16384,
                                 csr, deg, als2, ald2, xh2, Bi[1], c2v, c2s);
  k_L2<<<512, 512, 0, stream>>>(c2v, c2s, kW[2], kb[2], kpart+32768, lpW[2], lpb[2], poolw, mpart+32768,
                                mpart, kpart, beta, h0, out, donecnt);
}

// Round 6
// 243.156 us; speedup vs baseline: 1.0435x; 1.0435x over previous
//
#include <hip/hip_runtime.h>
#include <math.h>

// ---- static config (mirror of reference) ----
#define GNUM 4
#define NG 512
#define NN 2048
#define EE 32768
#define HC 128
#define HEADS 4
#define HID 32
#define GRID_PTS 500
#define QN 20
#define ODIM 32
#define MAXE 160              // per-dst edge cap (deg ~ Poisson(16); P(>159) ~ 0)

#define LOG2E 1.44269504088896340736f
#define NEG_HALF_LOG2E -0.72134752044448170368f
#define N_POW_M02 0.2871745887492588f   // 512^-0.2
#define SIG_K 144.269504089f            // 100 * log2(e)

typedef float v2f __attribute__((ext_vector_type(2)));

__device__ __forceinline__ float fexp2(float x){ return __builtin_amdgcn_exp2f(x); }
__device__ __forceinline__ float frcp(float x){ return __builtin_amdgcn_rcpf(x); }

struct SmemKDE {
  float4 wred4[8];
  float sc[4];
  float wsum[8], woff[9];
  float redw[QN][8], redg[QN][8];
  float qs[QN];
  float psum[512];             // upper-half partial densities
};
struct SmemXW  { float rows[8][HC]; int cnt[8]; };
struct SmemGat { int ssrc[8][MAXE]; float sexp[8][MAXE][HEADS]; };
struct SmemFin { float sdm[384]; };
union Smem { SmemKDE kde; SmemXW xw; SmemGat gat; SmemFin fin; };

// ---------------- KDE readout, FAT block: 1024 threads = 16 waves per (g,d) task -------------
// Sample planes vpl/spl [channel][node] = (v, v^2); uniform global float4 loads.
// Lower half (t<512): grid point t, samples 0..255.  Upper half: grid point t-512, samples
// 256..511.  Density = lowerSum + upperSum (one reordered add vs reference — tiny fp drift).
// 512 tasks x 16 waves = 8192 waves = 100% machine occupancy (thin 8-wave blocks capped at 50%).
__device__ void kde_fat(Smem& sm, const float* __restrict__ vpl, const float* __restrict__ spl,
        int b,
        const float* __restrict__ kW, const float* __restrict__ kb, float* __restrict__ kacc,
        const float* __restrict__ lpW, const float* __restrict__ lpb,
        const float* __restrict__ poolw, float* __restrict__ macc){
  int g = b >> 7, d = b & 127;
  int t = threadIdx.x;
  int lane = t & 63, wave = t >> 6;
  bool lower = t < 512;                  // wave-uniform (waves 0..7 lower, 8..15 upper)
  int gp = lower ? t : t - 512;          // grid point owned by this thread
  size_t base = (size_t)d*NN + g*NG;
  // ---- stats (lower half only; bit-identical to original 512-thread reduction) ----
  float v = 0.f, v2 = 0.f;
  if (lower){ v = vpl[base + t]; v2 = spl[base + t]; }
  float mn=v, mx=v, smv=v, sq=v2;
  #pragma unroll
  for (int m=32; m>0; m>>=1){
    mn = fminf(mn, __shfl_xor(mn, m, 64));
    mx = fmaxf(mx, __shfl_xor(mx, m, 64));
    smv += __shfl_xor(smv, m, 64);
    sq += __shfl_xor(sq, m, 64);
  }
  if (lower && lane==0) sm.kde.wred4[wave] = make_float4(mn,mx,smv,sq);
  __syncthreads();
  if (t==0){
    float4 r = sm.kde.wred4[0];
    #pragma unroll
    for (int i=1;i<8;++i){
      float4 bb = sm.kde.wred4[i];
      r.x = fminf(r.x,bb.x); r.y = fmaxf(r.y,bb.y); r.z += bb.z; r.w += bb.w;
    }
    float mean = r.z * (1.f/NG);
    float var  = fmaxf(r.w*(1.f/NG) - mean*mean, 0.f);
    float sd   = sqrtf(var) + (1e-8f/3.f);
    float h    = 1.06f * sd * N_POW_M02;
    float lo = r.x - 1e-6f, hi = r.y + 1e-6f;
    sm.kde.sc[0] = lo;
    sm.kde.sc[1] = (hi-lo)*(1.f/(GRID_PTS-1));
    sm.kde.sc[2] = NEG_HALF_LOG2E/(h*h);
    sm.kde.sc[3] = poolw[0]*mean + poolw[1]*r.y;
  }
  __syncthreads();
  float lo = sm.kde.sc[0], st = sm.kde.sc[1], kk = sm.kde.sc[2];
  float gv = lo + st*(float)gp;
  float acc = 0.f;
  {
    float c0 = kk*gv*gv, c1 = -2.f*kk*gv;
    v2f c0v = {c0, c0}, c1v = {c1, c1}, kkv = {kk, kk};
    const float4* pv = (const float4*)(vpl + base) + (lower ? 0 : 64);
    const float4* ps = (const float4*)(spl + base) + (lower ? 0 : 64);
    #pragma unroll 8
    for (int i=0;i<64;++i){
      float4 a = pv[i];      // 4 samples — uniform addr: 1 request/wave
      float4 bq = ps[i];     // their squares
      v2f alo = {a.x, a.y}, ahi = {a.z, a.w};
      v2f blo = {bq.x, bq.y}, bhi = {bq.z, bq.w};
      v2f plo = __builtin_elementwise_fma(kkv, blo, __builtin_elementwise_fma(c1v, alo, c0v));
      v2f phi = __builtin_elementwise_fma(kkv, bhi, __builtin_elementwise_fma(c1v, ahi, c0v));
      acc += fexp2(plo.x);
      acc += fexp2(plo.y);
      acc += fexp2(phi.x);
      acc += fexp2(phi.y);
    }
  }
  if (gp >= GRID_PTS) acc = 0.f;
  if (!lower) sm.kde.psum[gp] = acc;
  __syncthreads();
  if (lower) acc += sm.kde.psum[t];      // density = lowHalf + highHalf (the one reorder)
  // ---- inclusive scan over 500 grid points (lower half; identical to original) ----
  float sv = acc;
  #pragma unroll
  for (int off=1; off<64; off<<=1){
    float n = __shfl_up(sv, off, 64);
    if (lane >= off) sv += n;
  }
  if (lower && lane==63) sm.kde.wsum[wave] = sv;
  __syncthreads();
  if (t==0){
    float r2 = 0.f;
    #pragma unroll
    for (int i=0;i<8;++i){ sm.kde.woff[i]=r2; r2+=sm.kde.wsum[i]; }
    sm.kde.woff[8]=r2;
  }
  if (t < QN*8){ ((float*)sm.kde.redw)[t]=0.f; ((float*)sm.kde.redg)[t]=0.f; }
  __syncthreads();
  float invt = 1.f/fmaxf(sm.kde.woff[8], 1e-8f);
  if (lower){                             // wave-uniform branch; q-loop has no barriers
    float c = (sv + sm.kde.woff[wave]) * invt;
    float cw0 = __shfl(c, 0, 64), cw1 = __shfl(c, 63, 64);
    int qlo = max(0, (int)ceilf((cw0 - 0.17f)*(float)(QN-1)));
    int qhi = min(QN-1, (int)floorf((cw1 + 0.17f)*(float)(QN-1)));
    for (int q=qlo; q<=qhi; ++q){
      float w = 0.f;
      if (gp < GRID_PTS){
        float dist = fabsf(c - (float)q*(1.f/(QN-1)));
        w = frcp(1.f + fexp2(SIG_K*dist));
      }
      float gw = gv*w;
      #pragma unroll
      for (int m=32;m>0;m>>=1){
        w  += __shfl_xor(w,  m, 64);
        gw += __shfl_xor(gw, m, 64);
      }
      if (lane==0){ sm.kde.redw[q][wave]=w; sm.kde.redg[q][wave]=gw; }
    }
  }
  __syncthreads();
  if (t < QN){
    float sw=0.f, sgw=0.f;
    #pragma unroll
    for (int i=0;i<8;++i){ sw+=sm.kde.redw[t][i]; sgw+=sm.kde.redg[t][i]; }
    sm.kde.qs[t] = sgw / (sw + 1e-8f);
  }
  __syncthreads();
  if (t < ODIM){
    float a = 0.f;
    const float* kwb = kW + (size_t)d*QN*ODIM + t;
    #pragma unroll
    for (int q=0;q<QN;++q) a += sm.kde.qs[q]*kwb[q*ODIM];
    if (d==0) a += kb[t];
    kacc[(size_t)d*128 + g*ODIM + t] = a;           // dense partial, written exactly once
    float bb = sm.kde.sc[3]*lpW[d*ODIM + t];
    if (d==0) bb += lpb[t];
    macc[(size_t)d*128 + g*ODIM + t] = bb;
  }
  __syncthreads();
}

// ---------------- gather core (8 dst per 1024-thr block; returns channel value) ----------------
__device__ float gather_core(Smem& sm, int d, int sub, int tl,
        const int* __restrict__ csr, const int* __restrict__ deg,
        const float* __restrict__ als, const float* __restrict__ ald,
        const float* __restrict__ xh, const float* __restrict__ bias){
  int dg = deg[d];                       // already clamped to MAXE-1 at build time
  int E = dg + 1;                        // + self loop
  int Ep = (E + 7) & ~7;                 // padded length (pads contribute exactly 0)
  const int* base = csr + d*MAXE;
  float a0 = ald[d*4+0], a1 = ald[d*4+1], a2 = ald[d*4+2], a3 = ald[d*4+3];
  for (int i=tl; i<Ep; i+=128){
    int s = (i < dg) ? base[i] : d;
    sm.gat.ssrc[sub][i] = s;
    if (i < E){
      float4 av = *(const float4*)(als + (size_t)s*4);   // one 16B load
      float e0 = av.x+a0, e1 = av.y+a1, e2 = av.z+a2, e3 = av.w+a3;
      e0 = (e0>=0.f)? e0 : 0.2f*e0;
      e1 = (e1>=0.f)? e1 : 0.2f*e1;
      e2 = (e2>=0.f)? e2 : 0.2f*e2;
      e3 = (e3>=0.f)? e3 : 0.2f*e3;
      sm.gat.sexp[sub][i][0]=e0; sm.gat.sexp[sub][i][1]=e1;
      sm.gat.sexp[sub][i][2]=e2; sm.gat.sexp[sub][i][3]=e3;
    } else {
      sm.gat.sexp[sub][i][0]=0.f; sm.gat.sexp[sub][i][1]=0.f;
      sm.gat.sexp[sub][i][2]=0.f; sm.gat.sexp[sub][i][3]=0.f;
    }
  }
  __syncthreads();
  int h = tl >> 5, l32 = tl & 31;
  float mx = -INFINITY;
  for (int i=l32; i<E; i+=32) mx = fmaxf(mx, sm.gat.sexp[sub][i][h]);
  #pragma unroll
  for (int m=16; m>0; m>>=1) mx = fmaxf(mx, __shfl_xor(mx, m, 32));
  float sdn = 0.f;
  for (int i=l32; i<E; i+=32){
    float ev = fexp2(LOG2E*(sm.gat.sexp[sub][i][h] - mx));
    sm.gat.sexp[sub][i][h] = ev;         // head-local: same 32-lane group reads/writes
    sdn += ev;
  }
  #pragma unroll
  for (int m=16; m>0; m>>=1) sdn += __shfl_xor(sdn, m, 32);
  float fac = 1.f/(sdn + 1e-16f);
  float acc = bias[tl];
  for (int i0=0; i0<Ep; i0+=8){
    #pragma unroll
    for (int k=0;k<8;++k){
      int i = i0 + k;
      acc += sm.gat.sexp[sub][i][h]*fac * xh[(size_t)sm.gat.ssrc[sub][i]*HC + tl];
    }
  }
  __syncthreads();                        // gat LDS free for reuse after this
  return acc;
}

// ---------------- xw helper: GEMV row (in LDS rows[sub]) -> xh + logits ----------------
__device__ void xw_emit(Smem& sm, int sub, int j, int n,
        const float* __restrict__ W, const float* __restrict__ as_, const float* __restrict__ ad_,
        float* __restrict__ xh, float* __restrict__ als, float* __restrict__ ald){
  float acc = 0.f;
  #pragma unroll 8
  for (int c2=0;c2<HC;++c2)
    acc += sm.xw.rows[sub][c2]*W[(size_t)c2*HC + j];
  xh[(size_t)n*HC + j] = acc;
  int h = j >> 5, cc = j & 31;
  float ps = acc*as_[h*HID+cc], pd = acc*ad_[h*HID+cc];
  #pragma unroll
  for (int m=16;m>0;m>>=1){
    ps += __shfl_xor(ps, m, 32);
    pd += __shfl_xor(pd, m, 32);
  }
  if (cc==0){ als[n*HEADS+h]=ps; ald[n*HEADS+h]=pd; }
}

// ---------------- transpose write: rows[8][128] -> (v-plane, v^2-plane), 8 nodes ----------------
__device__ void write_transposed8(Smem& sm, int t, int n0,
                                  float* __restrict__ vpl, float* __restrict__ spl){
  if (t < HC){
    float r0 = sm.xw.rows[0][t], r1 = sm.xw.rows[1][t];
    float r2 = sm.xw.rows[2][t], r3 = sm.xw.rows[3][t];
    float r4 = sm.xw.rows[4][t], r5 = sm.xw.rows[5][t];
    float r6 = sm.xw.rows[6][t], r7 = sm.xw.rows[7][t];
    float4* pv = (float4*)(vpl + (size_t)t*NN + n0);
    float4* ps = (float4*)(spl + (size_t)t*NN + n0);
    pv[0] = make_float4(r0, r1, r2, r3);
    pv[1] = make_float4(r4, r5, r6, r7);
    ps[0] = make_float4(r0*r0, r1*r1, r2*r2, r3*r3);
    ps[1] = make_float4(r4*r4, r5*r5, r6*r6, r7*r7);
  }
}

// ================= T: x -> (xT v-plane, v^2-plane) =================
__global__ __launch_bounds__(512) void k_T(const float* __restrict__ x,
                                           float* __restrict__ vpl, float* __restrict__ spl){
  __shared__ float rows[4][HC];
  int t = threadIdx.x;
  int sub = t >> 7, j = t & 127;
  int n0 = blockIdx.x*4;
  rows[sub][j] = x[(size_t)(n0+sub)*HC + j];
  __syncthreads();
  if (t < HC){
    float v0 = rows[0][t], v1 = rows[1][t], v2 = rows[2][t], v3 = rows[3][t];
    *(float4*)(vpl + (size_t)t*NN + n0) = make_float4(v0, v1, v2, v3);
    *(float4*)(spl + (size_t)t*NN + n0) = make_float4(v0*v0, v1*v1, v2*v2, v3*v3);
  }
}

// ======= L0: fat-kde0 (bids 0..511) | xw0(x)+CSR, 8 nodes/block (bids 512..767) =======
__global__ __launch_bounds__(1024, 8) void k_L0(const float* __restrict__ x,
        const float* __restrict__ xTv, const float* __restrict__ xTs,
        const float* __restrict__ kW, const float* __restrict__ kb, float* __restrict__ kacc,
        const float* __restrict__ lpW, const float* __restrict__ lpb,
        const float* __restrict__ poolw, float* __restrict__ macc,
        const float* __restrict__ W, const float* __restrict__ as_, const float* __restrict__ ad_,
        float* __restrict__ xh, float* __restrict__ als, float* __restrict__ ald,
        const int* __restrict__ src, const int* __restrict__ dst,
        int* __restrict__ deg, int* __restrict__ csr){
  __shared__ Smem sm;
  int t = threadIdx.x;
  if (blockIdx.x < 512){
    kde_fat(sm, xTv, xTs, blockIdx.x, kW, kb, kacc, lpW, lpb, poolw, macc);
  } else {
    int b2 = blockIdx.x - 512;
    int sub = t >> 7, j = t & 127;
    int n = b2*8 + sub;
    if (t < 8) sm.xw.cnt[t] = 0;
    sm.xw.rows[sub][j] = x[(size_t)n*HC + j];
    __syncthreads();
    // CSR build: this block owns dst nodes [8*b2, 8*b2+8); scan all edges (L2-resident)
    int base8 = b2*8;
    for (int e = t; e < EE; e += 1024){
      int dd = dst[e];
      unsigned r = (unsigned)(dd - base8);
      if (r < 8u){
        int p = atomicAdd(&sm.xw.cnt[r], 1);
        if (p < MAXE) csr[dd*MAXE + p] = src[e];
      }
    }
    xw_emit(sm, sub, j, n, W, as_, ad_, xh, als, ald);
    __syncthreads();
    if (t < 8) deg[base8 + t] = min(sm.xw.cnt[t], MAXE-1);
  }
}

// ======= G0: gather0 -> cur1 planes (post-relu) + fused xw1; 8 dst/block, 256 blocks =======
__global__ __launch_bounds__(1024, 8) void k_G0(const int* __restrict__ csr, const int* __restrict__ deg,
        const float* __restrict__ als_in, const float* __restrict__ ald_in,
        const float* __restrict__ xh_in, const float* __restrict__ bias,
        float* __restrict__ c1v, float* __restrict__ c1s,
        const float* __restrict__ W1, const float* __restrict__ as1, const float* __restrict__ ad1,
        float* __restrict__ xh2, float* __restrict__ als2, float* __restrict__ ald2){
  __shared__ Smem sm;
  int t = threadIdx.x;
  int sub = t >> 7, tl = t & 127;
  int d = blockIdx.x*8 + sub;
  float acc = gather_core(sm, d, sub, tl, csr, deg, als_in, ald_in, xh_in, bias);
  sm.xw.rows[sub][tl] = fmaxf(acc, 0.f);   // post-relu: input to both kde1 and xw1
  __syncthreads();
  write_transposed8(sm, t, blockIdx.x*8, c1v, c1s);
  xw_emit(sm, sub, tl, d, W1, as1, ad1, xh2, als2, ald2);
}

// ======= L1: fat-kde1 (bids 0..511) | gather1 -> cur2 planes, 8 dst/block (bids 512..767) ==
__global__ __launch_bounds__(1024, 8) void k_L1(const float* __restrict__ c1v, const float* __restrict__ c1s,
        const float* __restrict__ kW, const float* __restrict__ kb, float* __restrict__ kacc,
        const float* __restrict__ lpW, const float* __restrict__ lpb,
        const float* __restrict__ poolw, float* __restrict__ macc,
        const int* __restrict__ csr, const int* __restrict__ deg,
        const float* __restrict__ als2, const float* __restrict__ ald2,
        const float* __restrict__ xh2, const float* __restrict__ bias,
        float* __restrict__ c2v, float* __restrict__ c2s){
  __shared__ Smem sm;
  int t = threadIdx.x;
  if (blockIdx.x < 512){
    kde_fat(sm, c1v, c1s, blockIdx.x, kW, kb, kacc, lpW, lpb, poolw, macc);
  } else {
    int b2 = blockIdx.x - 512;
    int sub = t >> 7, tl = t & 127;
    int d = b2*8 + sub;
    float acc = gather_core(sm, d, sub, tl, csr, deg, als2, ald2, xh2, bias);
    sm.xw.rows[sub][tl] = acc;             // no relu on last layer
    __syncthreads();
    write_transposed8(sm, t, b2*8, c2v, c2s);
  }
}

// ================= L2: fat-kde2 only (512 blocks, full occupancy) =================
__global__ __launch_bounds__(1024, 8) void k_L2(const float* __restrict__ c2v, const float* __restrict__ c2s,
        const float* __restrict__ kW, const float* __restrict__ kb, float* __restrict__ kacc,
        const float* __restrict__ lpW, const float* __restrict__ lpb,
        const float* __restrict__ poolw, float* __restrict__ macc){
  __shared__ Smem sm;
  kde_fat(sm, c2v, c2s, blockIdx.x, kW, kb, kacc, lpW, lpb, poolw, macc);
}

// ================= final: reduce dense partials [3][128 d][128 (g,o)] =================
__global__ __launch_bounds__(384) void k_final(const float* __restrict__ mpart, const float* __restrict__ kpart,
                        const float* __restrict__ beta, const float* __restrict__ h0,
                        float* __restrict__ out){
  int t = threadIdx.x;   // 384: l = t>>7, (g,o) = t&127
  __shared__ float sdm[384];
  int l = t >> 7, tt = t & 127;
  const float* mrow = mpart + (size_t)l*16384 + tt;
  const float* krow = kpart + (size_t)l*16384 + tt;
  float s = 0.f;
  #pragma unroll 8
  for (int d2=0; d2<128; ++d2) s += mrow[(size_t)d2*128] + krow[(size_t)d2*128];
  sdm[t] = s;
  __syncthreads();
  if (t < 128){
    int g = t >> 5, o = t & 31;
    float s3 = (sdm[t] + sdm[t+128] + sdm[t+256]) * (1.f/3.f) * beta[o];
    #pragma unroll
    for (int m=16; m>0; m>>=1) s3 += __shfl_xor(s3, m, 32);
    if (o == 0) out[g] = s3 + h0[0];
  }
}

extern "C" void kernel_launch(void* const* d_in, const int* in_sizes, int n_in,
                              void* d_out, int out_size, void* d_ws, size_t ws_size,
                              hipStream_t stream) {
  (void)in_sizes; (void)n_in; (void)out_size; (void)ws_size;
  const float* x    = (const float*)d_in[0];
  const int*   ei   = (const int*)d_in[1];
  const int*   srcp = ei;
  const int*   dstp = ei + EE;
  const float* W[2]   = {(const float*)d_in[3], (const float*)d_in[7]};
  const float* As[2]  = {(const float*)d_in[4], (const float*)d_in[8]};
  const float* Ad[2]  = {(const float*)d_in[5], (const float*)d_in[9]};
  const float* Bi[2]  = {(const float*)d_in[6], (const float*)d_in[10]};
  const float* lpW[3] = {(const float*)d_in[11], (const float*)d_in[13], (const float*)d_in[15]};
  const float* lpb[3] = {(const float*)d_in[12], (const float*)d_in[14], (const float*)d_in[16]};
  const float* kW[3]  = {(const float*)d_in[17], (const float*)d_in[19], (const float*)d_in[21]};
  const float* kb[3]  = {(const float*)d_in[18], (const float*)d_in[20], (const float*)d_in[22]};
  const float* poolw  = (const float*)d_in[23];
  const float* beta   = (const float*)d_in[24];
  const float* h0     = (const float*)d_in[25];
  float* out = (float*)d_out;

  // workspace layout (floats unless noted); all planes are [128][2048]
  float* ws = (float*)d_ws;
  float* xTv   = ws;                   // 262144
  float* xTs   = xTv + 262144;         // 262144
  float* c1v   = xTs + 262144;         // 262144
  float* c1s   = c1v + 262144;         // 262144
  float* c2v   = c1s + 262144;         // 262144
  float* c2s   = c2v + 262144;         // 262144
  float* xh    = c2s + 262144;         // 262144 (layer 0)
  float* xh2   = xh + 262144;          // 262144 (layer 1)
  float* als   = xh2 + 262144;         // 8192
  float* ald   = als + 8192;           // 8192
  float* als2  = ald + 8192;           // 8192
  float* ald2  = als2 + 8192;          // 8192
  float* mpart = ald2 + 8192;          // 3*128*128 = 49152 (dense, no init needed)
  float* kpart = mpart + 49152;        // 49152
  int*   deg   = (int*)(kpart + 49152);// 2048
  int*   csr   = deg + 2048;           // 2048*160

  k_T<<<512, 512, 0, stream>>>(x, xTv, xTs);
  k_L0<<<768, 1024, 0, stream>>>(x, xTv, xTs, kW[0], kb[0], kpart, lpW[0], lpb[0], poolw, mpart,
                                 W[0], As[0], Ad[0], xh, als, ald,
                                 srcp, dstp, deg, csr);
  k_G0<<<256, 1024, 0, stream>>>(csr, deg, als, ald, xh, Bi[0], c1v, c1s,
                                 W[1], As[1], Ad[1], xh2, als2, ald2);
  k_L1<<<768, 1024, 0, stream>>>(c1v, c1s, kW[1], kb[1], kpart+16384, lpW[1], lpb[1], poolw, mpart+16384,
                                 csr, deg, als2, ald2, xh2, Bi[1], c2v, c2s);
  k_L2<<<512, 1024, 0, stream>>>(c2v, c2s, kW[2], kb[2], kpart+32768, lpW[2], lpb[2], poolw, mpart+32768);
  k_final<<<1, 384, 0, stream>>>(mpart, kpart, beta, h0, out);
}

// Round 7
// 217.091 us; speedup vs baseline: 1.1688x; 1.1201x over previous
//
#include <hip/hip_runtime.h>
#include <math.h>

// ---- static config (mirror of reference) ----
#define GNUM 4
#define NG 512
#define NN 2048
#define EE 32768
#define HC 128
#define HEADS 4
#define HID 32
#define GRID_PTS 500
#define QN 20
#define ODIM 32
#define MAXE 160              // per-dst edge cap (deg ~ Poisson(16); P(>159) ~ 0)

#define LOG2E 1.44269504088896340736f
#define NEG_HALF_LOG2E -0.72134752044448170368f
#define N_POW_M02 0.2871745887492588f   // 512^-0.2
#define SIG_K 144.269504089f            // 100 * log2(e)

typedef float v2f __attribute__((ext_vector_type(2)));

__device__ __forceinline__ float fexp2(float x){ return __builtin_amdgcn_exp2f(x); }
__device__ __forceinline__ float frcp(float x){ return __builtin_amdgcn_rcpf(x); }

struct SmemKDE {
  __align__(16) float xs[NG];  // samples (v only) — 2KB; v^2 recomputed via pk_mul
  float4 wred4[8];
  float sc[4];
  float wsum[8], woff[9];
  float redw[QN][8], redg[QN][8];
  float qs[QN];
};
struct SmemXW  { float rows[4][HC]; int cnt[4]; };
struct SmemGat { int ssrc[4][MAXE]; float sexp[4][MAXE][HEADS]; };
union Smem { SmemKDE kde; SmemXW xw; SmemGat gat; };

// ---------------- KDE readout phase (one (g,d) per task b; b in [0,512)) ----------------
// SRC=0: cur is [node][channel] (layer-0 x), strided load. SRC=1: cur is transposed
// [channel][node], coalesced. Samples staged in LDS as v ONLY — main loop reads 4 samples
// per ds_read_b128 (half the LDS-port traffic of the (v,v^2) pair format) and recomputes
// v^2 with pk_mul (same v*v bits). Density sum split into two accumulators at the 256-sample
// boundary — the exact reorder verified absmax==0.0 in round 6.
// Partials dense (no atomics, no zero-init): kacc/macc laid out [d][g*32+o].
template<int SRC>
__device__ void kde_phase(Smem& sm, const float* __restrict__ cur, int b,
        const float* __restrict__ kW, const float* __restrict__ kb, float* __restrict__ kacc,
        const float* __restrict__ lpW, const float* __restrict__ lpb,
        const float* __restrict__ poolw, float* __restrict__ macc){
  int g = b >> 7, d = b & 127;
  int t = threadIdx.x;
  int lane = t & 63, wave = t >> 6;
  float v = SRC ? cur[(size_t)d*NN + g*NG + t]
                : cur[((size_t)g*NG + t)*HC + d];
  float v2 = v*v;
  sm.kde.xs[t] = v;
  float mn=v, mx=v, smv=v, sq=v2;
  #pragma unroll
  for (int m=32; m>0; m>>=1){
    mn = fminf(mn, __shfl_xor(mn, m, 64));
    mx = fmaxf(mx, __shfl_xor(mx, m, 64));
    smv += __shfl_xor(smv, m, 64);
    sq += __shfl_xor(sq, m, 64);
  }
  if (lane==0) sm.kde.wred4[wave] = make_float4(mn,mx,smv,sq);
  __syncthreads();
  if (t==0){
    float4 r = sm.kde.wred4[0];
    #pragma unroll
    for (int i=1;i<8;++i){
      float4 bb = sm.kde.wred4[i];
      r.x = fminf(r.x,bb.x); r.y = fmaxf(r.y,bb.y); r.z += bb.z; r.w += bb.w;
    }
    float mean = r.z * (1.f/NG);
    float var  = fmaxf(r.w*(1.f/NG) - mean*mean, 0.f);
    float sd   = sqrtf(var) + (1e-8f/3.f);
    float h    = 1.06f * sd * N_POW_M02;
    float lo = r.x - 1e-6f, hi = r.y + 1e-6f;
    sm.kde.sc[0] = lo;
    sm.kde.sc[1] = (hi-lo)*(1.f/(GRID_PTS-1));
    sm.kde.sc[2] = NEG_HALF_LOG2E/(h*h);
    sm.kde.sc[3] = poolw[0]*mean + poolw[1]*r.y;
  }
  __syncthreads();
  float lo = sm.kde.sc[0], st = sm.kde.sc[1], kk = sm.kde.sc[2];
  float gv = lo + st*(float)t;
  float accL = 0.f, accH = 0.f;
  {
    float c0 = kk*gv*gv, c1 = -2.f*kk*gv;
    v2f c0v = {c0, c0}, c1v = {c1, c1}, kkv = {kk, kk};
    const float4* p4 = (const float4*)sm.kde.xs;   // 128 x (4 samples)
    #pragma unroll 8
    for (int i=0;i<64;++i){                        // samples 0..255
      float4 s = p4[i];
      v2f a0 = {s.x, s.y}, a1 = {s.z, s.w};
      v2f q0 = a0*a0, q1 = a1*a1;                  // pk_mul: v^2 (same bits as v*v)
      v2f p0 = __builtin_elementwise_fma(kkv, q0, __builtin_elementwise_fma(c1v, a0, c0v));
      v2f p1 = __builtin_elementwise_fma(kkv, q1, __builtin_elementwise_fma(c1v, a1, c0v));
      accL += fexp2(p0.x); accL += fexp2(p0.y);
      accL += fexp2(p1.x); accL += fexp2(p1.y);
    }
    #pragma unroll 8
    for (int i=64;i<128;++i){                      // samples 256..511
      float4 s = p4[i];
      v2f a0 = {s.x, s.y}, a1 = {s.z, s.w};
      v2f q0 = a0*a0, q1 = a1*a1;
      v2f p0 = __builtin_elementwise_fma(kkv, q0, __builtin_elementwise_fma(c1v, a0, c0v));
      v2f p1 = __builtin_elementwise_fma(kkv, q1, __builtin_elementwise_fma(c1v, a1, c0v));
      accH += fexp2(p0.x); accH += fexp2(p0.y);
      accH += fexp2(p1.x); accH += fexp2(p1.y);
    }
  }
  float acc = accL + accH;        // round-6-verified reorder (halves the add dep chain)
  if (t >= GRID_PTS) acc = 0.f;   // mask lanes beyond the grid (kept out of hot loop)
  // inclusive scan
  float sv = acc;
  #pragma unroll
  for (int off=1; off<64; off<<=1){
    float n = __shfl_up(sv, off, 64);
    if (lane >= off) sv += n;
  }
  if (lane==63) sm.kde.wsum[wave] = sv;
  __syncthreads();
  if (t==0){
    float r2 = 0.f;
    #pragma unroll
    for (int i=0;i<8;++i){ sm.kde.woff[i]=r2; r2+=sm.kde.wsum[i]; }
    sm.kde.woff[8]=r2;
  }
  if (t < QN*8){ ((float*)sm.kde.redw)[t]=0.f; ((float*)sm.kde.redg)[t]=0.f; }
  __syncthreads();
  float invt = 1.f/fmaxf(sm.kde.woff[8], 1e-8f);
  float c = (sv + sm.kde.woff[wave]) * invt;
  float cw0 = __shfl(c, 0, 64), cw1 = __shfl(c, 63, 64);
  int qlo = max(0, (int)ceilf((cw0 - 0.17f)*(float)(QN-1)));
  int qhi = min(QN-1, (int)floorf((cw1 + 0.17f)*(float)(QN-1)));
  for (int q=qlo; q<=qhi; ++q){
    float w = 0.f;
    if (t < GRID_PTS){
      float dist = fabsf(c - (float)q*(1.f/(QN-1)));
      w = frcp(1.f + fexp2(SIG_K*dist));
    }
    float gw = gv*w;
    #pragma unroll
    for (int m=32;m>0;m>>=1){
      w  += __shfl_xor(w,  m, 64);
      gw += __shfl_xor(gw, m, 64);
    }
    if (lane==0){ sm.kde.redw[q][wave]=w; sm.kde.redg[q][wave]=gw; }
  }
  __syncthreads();
  if (t < QN){
    float sw=0.f, sgw=0.f;
    #pragma unroll
    for (int i=0;i<8;++i){ sw+=sm.kde.redw[t][i]; sgw+=sm.kde.redg[t][i]; }
    sm.kde.qs[t] = sgw / (sw + 1e-8f);
  }
  __syncthreads();
  if (t < ODIM){
    float a = 0.f;
    const float* kwb = kW + (size_t)d*QN*ODIM + t;
    #pragma unroll
    for (int q=0;q<QN;++q) a += sm.kde.qs[q]*kwb[q*ODIM];
    if (d==0) a += kb[t];
    kacc[(size_t)d*128 + g*ODIM + t] = a;           // dense partial, written exactly once
    float bb = sm.kde.sc[3]*lpW[d*ODIM + t];
    if (d==0) bb += lpb[t];
    macc[(size_t)d*128 + g*ODIM + t] = bb;
  }
  __syncthreads();
}

// ---------------- gather core (4 dst/block; returns this thread's channel value) ----------------
__device__ float gather_core(Smem& sm, int d, int sub, int tl,
        const int* __restrict__ csr, const int* __restrict__ deg,
        const float* __restrict__ als, const float* __restrict__ ald,
        const float* __restrict__ xh, const float* __restrict__ bias){
  int dg = deg[d];                       // already clamped to MAXE-1 at build time
  int E = dg + 1;                        // + self loop
  int Ep = (E + 7) & ~7;                 // padded length (pads contribute exactly 0)
  const int* base = csr + d*MAXE;
  float a0 = ald[d*4+0], a1 = ald[d*4+1], a2 = ald[d*4+2], a3 = ald[d*4+3];
  for (int i=tl; i<Ep; i+=128){
    int s = (i < dg) ? base[i] : d;
    sm.gat.ssrc[sub][i] = s;
    if (i < E){
      float4 av = *(const float4*)(als + (size_t)s*4);   // one 16B load
      float e0 = av.x+a0, e1 = av.y+a1, e2 = av.z+a2, e3 = av.w+a3;
      e0 = (e0>=0.f)? e0 : 0.2f*e0;
      e1 = (e1>=0.f)? e1 : 0.2f*e1;
      e2 = (e2>=0.f)? e2 : 0.2f*e2;
      e3 = (e3>=0.f)? e3 : 0.2f*e3;
      sm.gat.sexp[sub][i][0]=e0; sm.gat.sexp[sub][i][1]=e1;
      sm.gat.sexp[sub][i][2]=e2; sm.gat.sexp[sub][i][3]=e3;
    } else {
      sm.gat.sexp[sub][i][0]=0.f; sm.gat.sexp[sub][i][1]=0.f;
      sm.gat.sexp[sub][i][2]=0.f; sm.gat.sexp[sub][i][3]=0.f;
    }
  }
  __syncthreads();
  int h = tl >> 5, l32 = tl & 31;
  float mx = -INFINITY;
  for (int i=l32; i<E; i+=32) mx = fmaxf(mx, sm.gat.sexp[sub][i][h]);
  #pragma unroll
  for (int m=16; m>0; m>>=1) mx = fmaxf(mx, __shfl_xor(mx, m, 32));
  float sdn = 0.f;
  for (int i=l32; i<E; i+=32){
    float ev = fexp2(LOG2E*(sm.gat.sexp[sub][i][h] - mx));
    sm.gat.sexp[sub][i][h] = ev;         // head-local: same 32-lane group reads/writes
    sdn += ev;
  }
  #pragma unroll
  for (int m=16; m>0; m>>=1) sdn += __shfl_xor(sdn, m, 32);
  float fac = 1.f/(sdn + 1e-16f);
  float acc = bias[tl];
  for (int i0=0; i0<Ep; i0+=8){
    #pragma unroll
    for (int k=0;k<8;++k){
      int i = i0 + k;
      acc += sm.gat.sexp[sub][i][h]*fac * xh[(size_t)sm.gat.ssrc[sub][i]*HC + tl];
    }
  }
  __syncthreads();                        // gat LDS free for reuse after this
  return acc;
}

// ---------------- xw helper: GEMV row (in LDS rows[sub]) -> xh + logits ----------------
__device__ void xw_emit(Smem& sm, int sub, int j, int n,
        const float* __restrict__ W, const float* __restrict__ as_, const float* __restrict__ ad_,
        float* __restrict__ xh, float* __restrict__ als, float* __restrict__ ald){
  float acc = 0.f;
  #pragma unroll 8
  for (int c2=0;c2<HC;++c2)
    acc += sm.xw.rows[sub][c2]*W[(size_t)c2*HC + j];
  xh[(size_t)n*HC + j] = acc;
  int h = j >> 5, cc = j & 31;
  float ps = acc*as_[h*HID+cc], pd = acc*ad_[h*HID+cc];
  #pragma unroll
  for (int m=16;m>0;m>>=1){
    ps += __shfl_xor(ps, m, 32);
    pd += __shfl_xor(pd, m, 32);
  }
  if (cc==0){ als[n*HEADS+h]=ps; ald[n*HEADS+h]=pd; }
}

// ---------------- transpose write: rows[4][128] -> single v-plane ----------------
__device__ void write_transposed(Smem& sm, int t, int n0, float* __restrict__ vpl){
  if (t < HC){
    float v0 = sm.xw.rows[0][t], v1 = sm.xw.rows[1][t];
    float v2 = sm.xw.rows[2][t], v3 = sm.xw.rows[3][t];
    *(float4*)(vpl + (size_t)t*NN + n0) = make_float4(v0, v1, v2, v3);
  }
}

// ================= L0: kde0(x, bids 0..511) | xw0(x)+CSR (bids 512..1023) =========
__global__ __launch_bounds__(512) void k_L0(const float* __restrict__ x,
        const float* __restrict__ kW, const float* __restrict__ kb, float* __restrict__ kacc,
        const float* __restrict__ lpW, const float* __restrict__ lpb,
        const float* __restrict__ poolw, float* __restrict__ macc,
        const float* __restrict__ W, const float* __restrict__ as_, const float* __restrict__ ad_,
        float* __restrict__ xh, float* __restrict__ als, float* __restrict__ ald,
        const int* __restrict__ src, const int* __restrict__ dst,
        int* __restrict__ deg, int* __restrict__ csr){
  __shared__ Smem sm;
  int t = threadIdx.x;
  if (blockIdx.x < 512){
    kde_phase<0>(sm, x, blockIdx.x, kW, kb, kacc, lpW, lpb, poolw, macc);
  } else {
    int b2 = blockIdx.x - 512;
    int sub = t >> 7, j = t & 127;
    int n = b2*4 + sub;
    if (t < 4) sm.xw.cnt[t] = 0;
    sm.xw.rows[sub][j] = x[(size_t)n*HC + j];
    __syncthreads();
    // CSR build: this block owns dst nodes [4*b2, 4*b2+4); scan all edges (L2-resident)
    int base4 = b2*4;
    for (int e = t; e < EE; e += 512){
      int dd = dst[e];
      unsigned r = (unsigned)(dd - base4);
      if (r < 4u){
        int p = atomicAdd(&sm.xw.cnt[r], 1);
        if (p < MAXE) csr[dd*MAXE + p] = src[e];
      }
    }
    xw_emit(sm, sub, j, n, W, as_, ad_, xh, als, ald);
    __syncthreads();
    if (t < 4) deg[base4 + t] = min(sm.xw.cnt[t], MAXE-1);
  }
}

// ================= G0: gather0 -> cur1 plane (post-relu) + fused xw1 =================
__global__ __launch_bounds__(512) void k_G0(const int* __restrict__ csr, const int* __restrict__ deg,
        const float* __restrict__ als_in, const float* __restrict__ ald_in,
        const float* __restrict__ xh_in, const float* __restrict__ bias,
        float* __restrict__ c1v,
        const float* __restrict__ W1, const float* __restrict__ as1, const float* __restrict__ ad1,
        float* __restrict__ xh2, float* __restrict__ als2, float* __restrict__ ald2){
  __shared__ Smem sm;
  int t = threadIdx.x;
  int sub = t >> 7, tl = t & 127;
  int d = blockIdx.x*4 + sub;
  float acc = gather_core(sm, d, sub, tl, csr, deg, als_in, ald_in, xh_in, bias);
  sm.xw.rows[sub][tl] = fmaxf(acc, 0.f);   // post-relu: input to both kde1 and xw1
  __syncthreads();
  write_transposed(sm, t, blockIdx.x*4, c1v);
  xw_emit(sm, sub, tl, d, W1, as1, ad1, xh2, als2, ald2);
}

// ================= L1: kde1(c1, bids 0..511) | gather1 -> cur2 plane (bids 512..1023) =====
__global__ __launch_bounds__(512) void k_L1(const float* __restrict__ c1v,
        const float* __restrict__ kW, const float* __restrict__ kb, float* __restrict__ kacc,
        const float* __restrict__ lpW, const float* __restrict__ lpb,
        const float* __restrict__ poolw, float* __restrict__ macc,
        const int* __restrict__ csr, const int* __restrict__ deg,
        const float* __restrict__ als2, const float* __restrict__ ald2,
        const float* __restrict__ xh2, const float* __restrict__ bias,
        float* __restrict__ c2v){
  __shared__ Smem sm;
  int t = threadIdx.x;
  if (blockIdx.x < 512){
    kde_phase<1>(sm, c1v, blockIdx.x, kW, kb, kacc, lpW, lpb, poolw, macc);
  } else {
    int b2 = blockIdx.x - 512;
    int sub = t >> 7, tl = t & 127;
    int d = b2*4 + sub;
    float acc = gather_core(sm, d, sub, tl, csr, deg, als2, ald2, xh2, bias);
    sm.xw.rows[sub][tl] = acc;             // no relu on last layer
    __syncthreads();
    write_transposed(sm, t, b2*4, c2v);
  }
}

// ================= L2: kde2(c2) only =================
__global__ __launch_bounds__(512) void k_L2(const float* __restrict__ c2v,
        const float* __restrict__ kW, const float* __restrict__ kb, float* __restrict__ kacc,
        const float* __restrict__ lpW, const float* __restrict__ lpb,
        const float* __restrict__ poolw, float* __restrict__ macc){
  __shared__ Smem sm;
  kde_phase<1>(sm, c2v, blockIdx.x, kW, kb, kacc, lpW, lpb, poolw, macc);
}

// ================= final: reduce dense partials [3][128 d][128 (g,o)] =================
__global__ __launch_bounds__(384) void k_final(const float* __restrict__ mpart, const float* __restrict__ kpart,
                        const float* __restrict__ beta, const float* __restrict__ h0,
                        float* __restrict__ out){
  int t = threadIdx.x;   // 384: l = t>>7, (g,o) = t&127
  __shared__ float sdm[384];
  int l = t >> 7, tt = t & 127;
  const float* mrow = mpart + (size_t)l*16384 + tt;
  const float* krow = kpart + (size_t)l*16384 + tt;
  float s = 0.f;
  #pragma unroll 8
  for (int d2=0; d2<128; ++d2) s += mrow[(size_t)d2*128] + krow[(size_t)d2*128];
  sdm[t] = s;
  __syncthreads();
  if (t < 128){
    int g = t >> 5, o = t & 31;
    float s3 = (sdm[t] + sdm[t+128] + sdm[t+256]) * (1.f/3.f) * beta[o];
    #pragma unroll
    for (int m=16; m>0; m>>=1) s3 += __shfl_xor(s3, m, 32);
    if (o == 0) out[g] = s3 + h0[0];
  }
}

extern "C" void kernel_launch(void* const* d_in, const int* in_sizes, int n_in,
                              void* d_out, int out_size, void* d_ws, size_t ws_size,
                              hipStream_t stream) {
  (void)in_sizes; (void)n_in; (void)out_size; (void)ws_size;
  const float* x    = (const float*)d_in[0];
  const int*   ei   = (const int*)d_in[1];
  const int*   srcp = ei;
  const int*   dstp = ei + EE;
  const float* W[2]   = {(const float*)d_in[3], (const float*)d_in[7]};
  const float* As[2]  = {(const float*)d_in[4], (const float*)d_in[8]};
  const float* Ad[2]  = {(const float*)d_in[5], (const float*)d_in[9]};
  const float* Bi[2]  = {(const float*)d_in[6], (const float*)d_in[10]};
  const float* lpW[3] = {(const float*)d_in[11], (const float*)d_in[13], (const float*)d_in[15]};
  const float* lpb[3] = {(const float*)d_in[12], (const float*)d_in[14], (const float*)d_in[16]};
  const float* kW[3]  = {(const float*)d_in[17], (const float*)d_in[19], (const float*)d_in[21]};
  const float* kb[3]  = {(const float*)d_in[18], (const float*)d_in[20], (const float*)d_in[22]};
  const float* poolw  = (const float*)d_in[23];
  const float* beta   = (const float*)d_in[24];
  const float* h0     = (const float*)d_in[25];
  float* out = (float*)d_out;

  // workspace layout (floats unless noted); c1/c2 are single transposed planes [128][2048]
  float* ws = (float*)d_ws;
  float* c1v   = ws;                   // 262144
  float* c2v   = c1v + 262144;         // 262144
  float* xh    = c2v + 262144;         // 262144 (layer 0)
  float* xh2   = xh + 262144;          // 262144 (layer 1)
  float* als   = xh2 + 262144;         // 8192
  float* ald   = als + 8192;           // 8192
  float* als2  = ald + 8192;           // 8192
  float* ald2  = als2 + 8192;          // 8192
  float* mpart = ald2 + 8192;          // 3*128*128 = 49152 (dense, no init needed)
  float* kpart = mpart + 49152;        // 49152
  int*   deg   = (int*)(kpart + 49152);// 2048
  int*   csr   = deg + 2048;           // 2048*160

  k_L0<<<1024, 512, 0, stream>>>(x, kW[0], kb[0], kpart, lpW[0], lpb[0], poolw, mpart,
                                 W[0], As[0], Ad[0], xh, als, ald,
                                 srcp, dstp, deg, csr);
  k_G0<<<512, 512, 0, stream>>>(csr, deg, als, ald, xh, Bi[0], c1v,
                                W[1], As[1], Ad[1], xh2, als2, ald2);
  k_L1<<<1024, 512, 0, stream>>>(c1v, kW[1], kb[1], kpart+16384, lpW[1], lpb[1], poolw, mpart+16384,
                                 csr, deg, als2, ald2, xh2, Bi[1], c2v);
  k_L2<<<512, 512, 0, stream>>>(c2v, kW[2], kb[2], kpart+32768, lpW[2], lpb[2], poolw, mpart+32768);
  k_final<<<1, 384, 0, stream>>>(mpart, kpart, beta, h0, out);
}

// Round 8
// 211.545 us; speedup vs baseline: 1.1994x; 1.0262x over previous
//
#include <hip/hip_runtime.h>
#include <math.h>

// ---- static config (mirror of reference) ----
#define GNUM 4
#define NG 512
#define NN 2048
#define EE 32768
#define HC 128
#define HEADS 4
#define HID 32
#define GRID_PTS 500
#define QN 20
#define ODIM 32
#define MAXE 160              // per-dst edge cap (deg ~ Poisson(16); P(>159) ~ 0)

#define LOG2E 1.44269504088896340736f
#define NEG_HALF_LOG2E -0.72134752044448170368f
#define N_POW_M02 0.2871745887492588f   // 512^-0.2
#define SIG_K 144.269504089f            // 100 * log2(e)

typedef float v2f __attribute__((ext_vector_type(2)));

__device__ __forceinline__ float fexp2(float x){ return __builtin_amdgcn_exp2f(x); }
__device__ __forceinline__ float frcp(float x){ return __builtin_amdgcn_rcpf(x); }

struct SmemKDE {
  __align__(16) float2 xs[NG];   // (v, v^2) pair staging — PLANE=0 (layer-0) path only
  float4 wred4[8];
  float wsum[8];
  float redw[QN][8], redg[QN][8];
  float qs[QN];
};
struct SmemXW  { float rows[4][HC]; int cnt[4]; };
struct SmemGat { int ssrc[4][MAXE]; float sexp[4][MAXE][HEADS]; };
union Smem { SmemKDE kde; SmemXW xw; SmemGat gat; };

// ---------------- KDE readout phase (one (g,d) per task b; b in [0,512)) ----------------
// PLANE=1: samples in two planes vpl/spl [channel][node] (v, v^2); global-uniform float4
//          loads + pk_fma (round-4 measured-best trans path).
// PLANE=0: xsrc is [node][channel] (layer-0 x); strided load staged to LDS as (v,v^2)
//          pairs (round-1 measured-best layer-0 path).
// SLIM sync: 4 barriers, no serial t==0 phases — cross-wave combines are done redundantly
// by every thread in the identical order (bit-identical results, idle-wave time -> VALU).
// Partials dense (no atomics, no zero-init): kacc/macc laid out [d][g*32+o].
template<int PLANE>
__device__ void kde_phase(Smem& sm, const float* __restrict__ vpl, const float* __restrict__ spl,
        const float* __restrict__ xsrc, int b,
        const float* __restrict__ kW, const float* __restrict__ kb, float* __restrict__ kacc,
        const float* __restrict__ lpW, const float* __restrict__ lpb,
        const float* __restrict__ poolw, float* __restrict__ macc){
  int g = b >> 7, d = b & 127;
  int t = threadIdx.x;
  int lane = t & 63, wave = t >> 6;
  size_t base = (size_t)d*NN + g*NG;
  float v, v2;
  if (PLANE){
    v  = vpl[base + t];
    v2 = spl[base + t];
  } else {
    v = xsrc[((size_t)g*NG + t)*HC + d];
    v2 = v*v;
    sm.kde.xs[t] = make_float2(v, v2);
  }
  float mn=v, mx=v, smv=v, sq=v2;
  #pragma unroll
  for (int m=32; m>0; m>>=1){
    mn = fminf(mn, __shfl_xor(mn, m, 64));
    mx = fmaxf(mx, __shfl_xor(mx, m, 64));
    smv += __shfl_xor(smv, m, 64);
    sq += __shfl_xor(sq, m, 64);
  }
  if (lane==0) sm.kde.wred4[wave] = make_float4(mn,mx,smv,sq);
  __syncthreads();                                   // barrier 1 (covers xs + wred4)
  // all threads combine waves locally — same order as the old t==0 phase -> identical bits
  float4 r = sm.kde.wred4[0];
  #pragma unroll
  for (int i=1;i<8;++i){
    float4 bb = sm.kde.wred4[i];
    r.x = fminf(r.x,bb.x); r.y = fmaxf(r.y,bb.y); r.z += bb.z; r.w += bb.w;
  }
  float mean = r.z * (1.f/NG);
  float var  = fmaxf(r.w*(1.f/NG) - mean*mean, 0.f);
  float sd   = sqrtf(var) + (1e-8f/3.f);
  float hh   = 1.06f * sd * N_POW_M02;
  float lo = r.x - 1e-6f, hi = r.y + 1e-6f;
  float st = (hi-lo)*(1.f/(GRID_PTS-1));
  float kk = NEG_HALF_LOG2E/(hh*hh);
  float pool = poolw[0]*mean + poolw[1]*r.y;
  float gv = lo + st*(float)t;
  float acc = 0.f;
  if (PLANE){
    float c0 = kk*gv*gv, c1 = -2.f*kk*gv;
    v2f c0v = {c0, c0}, c1v = {c1, c1}, kkv = {kk, kk};
    const float4* pv = (const float4*)(vpl + base);
    const float4* ps = (const float4*)(spl + base);
    #pragma unroll 8
    for (int i=0;i<NG/4;++i){
      float4 a = pv[i];      // x0..x3   — uniform addr: 1 request/wave
      float4 bq = ps[i];     // x0^2..x3^2
      v2f alo = {a.x, a.y}, ahi = {a.z, a.w};
      v2f blo = {bq.x, bq.y}, bhi = {bq.z, bq.w};
      v2f plo = __builtin_elementwise_fma(kkv, blo, __builtin_elementwise_fma(c1v, alo, c0v));
      v2f phi = __builtin_elementwise_fma(kkv, bhi, __builtin_elementwise_fma(c1v, ahi, c0v));
      acc += fexp2(plo.x);
      acc += fexp2(plo.y);
      acc += fexp2(phi.x);
      acc += fexp2(phi.y);
    }
  } else {
    float c0 = kk*gv*gv, c1 = -2.f*kk*gv;
    const float4* p4 = (const float4*)sm.kde.xs;
    #pragma unroll 4
    for (int i=0;i<NG/2;++i){
      float4 s2 = p4[i];     // (x0, x0^2, x1, x1^2)
      acc += fexp2(fmaf(kk, s2.y, fmaf(c1, s2.x, c0)));
      acc += fexp2(fmaf(kk, s2.w, fmaf(c1, s2.z, c0)));
    }
  }
  if (t >= GRID_PTS) acc = 0.f;   // mask lanes beyond the grid (kept out of hot loop)
  // inclusive scan
  float sv = acc;
  #pragma unroll
  for (int off=1; off<64; off<<=1){
    float n = __shfl_up(sv, off, 64);
    if (lane >= off) sv += n;
  }
  if (lane==63) sm.kde.wsum[wave] = sv;
  if (t < QN*8){ ((float*)sm.kde.redw)[t]=0.f; ((float*)sm.kde.redg)[t]=0.f; }
  __syncthreads();                                   // barrier 2 (covers wsum + red init)
  // local prefix over wsum — same ascending order as the old t==0 phase -> identical bits
  float woff = 0.f, tot = 0.f;
  #pragma unroll
  for (int i=0;i<8;++i){
    if (i == wave) woff = tot;
    tot += sm.kde.wsum[i];
  }
  float invt = 1.f/fmaxf(tot, 1e-8f);
  float c = (sv + woff) * invt;
  float cw0 = __shfl(c, 0, 64), cw1 = __shfl(c, 63, 64);
  int qlo = max(0, (int)ceilf((cw0 - 0.17f)*(float)(QN-1)));
  int qhi = min(QN-1, (int)floorf((cw1 + 0.17f)*(float)(QN-1)));
  for (int q=qlo; q<=qhi; ++q){
    float w = 0.f;
    if (t < GRID_PTS){
      float dist = fabsf(c - (float)q*(1.f/(QN-1)));
      w = frcp(1.f + fexp2(SIG_K*dist));
    }
    float gw = gv*w;
    #pragma unroll
    for (int m=32;m>0;m>>=1){
      w  += __shfl_xor(w,  m, 64);
      gw += __shfl_xor(gw, m, 64);
    }
    if (lane==0){ sm.kde.redw[q][wave]=w; sm.kde.redg[q][wave]=gw; }
  }
  __syncthreads();                                   // barrier 3
  if (t < QN){
    float sw=0.f, sgw=0.f;
    #pragma unroll
    for (int i=0;i<8;++i){ sw+=sm.kde.redw[t][i]; sgw+=sm.kde.redg[t][i]; }
    sm.kde.qs[t] = sgw / (sw + 1e-8f);
  }
  __syncthreads();                                   // barrier 4
  if (t < ODIM){
    float a = 0.f;
    const float* kwb = kW + (size_t)d*QN*ODIM + t;
    #pragma unroll
    for (int q=0;q<QN;++q) a += sm.kde.qs[q]*kwb[q*ODIM];
    if (d==0) a += kb[t];
    kacc[(size_t)d*128 + g*ODIM + t] = a;           // dense partial, written exactly once
    float bb = pool*lpW[d*ODIM + t];
    if (d==0) bb += lpb[t];
    macc[(size_t)d*128 + g*ODIM + t] = bb;
  }
  // no trailing barrier: each block runs exactly one task
}

// ---------------- gather core (4 dst/block; returns this thread's channel value) ----------------
__device__ float gather_core(Smem& sm, int d, int sub, int tl,
        const int* __restrict__ csr, const int* __restrict__ deg,
        const float* __restrict__ als, const float* __restrict__ ald,
        const float* __restrict__ xh, const float* __restrict__ bias){
  int dg = deg[d];                       // already clamped to MAXE-1 at build time
  int E = dg + 1;                        // + self loop
  int Ep = (E + 7) & ~7;                 // padded length (pads contribute exactly 0)
  const int* base = csr + d*MAXE;
  float a0 = ald[d*4+0], a1 = ald[d*4+1], a2 = ald[d*4+2], a3 = ald[d*4+3];
  for (int i=tl; i<Ep; i+=128){
    int s = (i < dg) ? base[i] : d;
    sm.gat.ssrc[sub][i] = s;
    if (i < E){
      float4 av = *(const float4*)(als + (size_t)s*4);   // one 16B load
      float e0 = av.x+a0, e1 = av.y+a1, e2 = av.z+a2, e3 = av.w+a3;
      e0 = (e0>=0.f)? e0 : 0.2f*e0;
      e1 = (e1>=0.f)? e1 : 0.2f*e1;
      e2 = (e2>=0.f)? e2 : 0.2f*e2;
      e3 = (e3>=0.f)? e3 : 0.2f*e3;
      sm.gat.sexp[sub][i][0]=e0; sm.gat.sexp[sub][i][1]=e1;
      sm.gat.sexp[sub][i][2]=e2; sm.gat.sexp[sub][i][3]=e3;
    } else {
      sm.gat.sexp[sub][i][0]=0.f; sm.gat.sexp[sub][i][1]=0.f;
      sm.gat.sexp[sub][i][2]=0.f; sm.gat.sexp[sub][i][3]=0.f;
    }
  }
  __syncthreads();
  int h = tl >> 5, l32 = tl & 31;
  float mx = -INFINITY;
  for (int i=l32; i<E; i+=32) mx = fmaxf(mx, sm.gat.sexp[sub][i][h]);
  #pragma unroll
  for (int m=16; m>0; m>>=1) mx = fmaxf(mx, __shfl_xor(mx, m, 32));
  float sdn = 0.f;
  for (int i=l32; i<E; i+=32){
    float ev = fexp2(LOG2E*(sm.gat.sexp[sub][i][h] - mx));
    sm.gat.sexp[sub][i][h] = ev;         // head-local: same 32-lane group reads/writes
    sdn += ev;
  }
  #pragma unroll
  for (int m=16; m>0; m>>=1) sdn += __shfl_xor(sdn, m, 32);
  float fac = 1.f/(sdn + 1e-16f);
  float acc = bias[tl];
  for (int i0=0; i0<Ep; i0+=8){
    #pragma unroll
    for (int k=0;k<8;++k){
      int i = i0 + k;
      acc += sm.gat.sexp[sub][i][h]*fac * xh[(size_t)sm.gat.ssrc[sub][i]*HC + tl];
    }
  }
  __syncthreads();                        // gat LDS free for reuse after this
  return acc;
}

// ---------------- xw helper: GEMV row (in LDS rows[sub]) -> xh + logits ----------------
__device__ void xw_emit(Smem& sm, int sub, int j, int n,
        const float* __restrict__ W, const float* __restrict__ as_, const float* __restrict__ ad_,
        float* __restrict__ xh, float* __restrict__ als, float* __restrict__ ald){
  float acc = 0.f;
  #pragma unroll 8
  for (int c2=0;c2<HC;++c2)
    acc += sm.xw.rows[sub][c2]*W[(size_t)c2*HC + j];
  xh[(size_t)n*HC + j] = acc;
  int h = j >> 5, cc = j & 31;
  float ps = acc*as_[h*HID+cc], pd = acc*ad_[h*HID+cc];
  #pragma unroll
  for (int m=16;m>0;m>>=1){
    ps += __shfl_xor(ps, m, 32);
    pd += __shfl_xor(pd, m, 32);
  }
  if (cc==0){ als[n*HEADS+h]=ps; ald[n*HEADS+h]=pd; }
}

// ---------------- transpose write: rows[4][128] -> (v-plane, v^2-plane) ----------------
__device__ void write_transposed(Smem& sm, int t, int n0,
                                 float* __restrict__ vpl, float* __restrict__ spl){
  if (t < HC){
    float v0 = sm.xw.rows[0][t], v1 = sm.xw.rows[1][t];
    float v2 = sm.xw.rows[2][t], v3 = sm.xw.rows[3][t];
    *(float4*)(vpl + (size_t)t*NN + n0) = make_float4(v0, v1, v2, v3);
    *(float4*)(spl + (size_t)t*NN + n0) = make_float4(v0*v0, v1*v1, v2*v2, v3*v3);
  }
}

// ======= L0: xw0(x)+CSR (bids 0..511) | kde0 tasks 0..255 LDS-pair path (bids 512..767) =====
__global__ __launch_bounds__(512) void k_L0(const float* __restrict__ x,
        const float* __restrict__ kW, const float* __restrict__ kb, float* __restrict__ kacc,
        const float* __restrict__ lpW, const float* __restrict__ lpb,
        const float* __restrict__ poolw, float* __restrict__ macc,
        const float* __restrict__ W, const float* __restrict__ as_, const float* __restrict__ ad_,
        float* __restrict__ xh, float* __restrict__ als, float* __restrict__ ald,
        const int* __restrict__ src, const int* __restrict__ dst,
        int* __restrict__ deg, int* __restrict__ csr){
  __shared__ Smem sm;
  int t = threadIdx.x;
  if (blockIdx.x >= 512){
    kde_phase<0>(sm, nullptr, nullptr, x, blockIdx.x - 512, kW, kb, kacc, lpW, lpb, poolw, macc);
  } else {
    int b2 = blockIdx.x;
    int sub = t >> 7, j = t & 127;
    int n = b2*4 + sub;
    if (t < 4) sm.xw.cnt[t] = 0;
    sm.xw.rows[sub][j] = x[(size_t)n*HC + j];
    __syncthreads();
    // CSR build: this block owns dst nodes [4*b2, 4*b2+4); scan all edges (L2-resident)
    int base4 = b2*4;
    for (int e = t; e < EE; e += 512){
      int dd = dst[e];
      unsigned r = (unsigned)(dd - base4);
      if (r < 4u){
        int p = atomicAdd(&sm.xw.cnt[r], 1);
        if (p < MAXE) csr[dd*MAXE + p] = src[e];
      }
    }
    xw_emit(sm, sub, j, n, W, as_, ad_, xh, als, ald);
    __syncthreads();
    if (t < 4) deg[base4 + t] = min(sm.xw.cnt[t], MAXE-1);
  }
}

// ==== G0: gather0+xw1 -> cur1 planes (bids 0..511) | kde0 tasks 256..511 (bids 512..767) ====
__global__ __launch_bounds__(512) void k_G0(const int* __restrict__ csr, const int* __restrict__ deg,
        const float* __restrict__ als_in, const float* __restrict__ ald_in,
        const float* __restrict__ xh_in, const float* __restrict__ bias,
        float* __restrict__ c1v, float* __restrict__ c1s,
        const float* __restrict__ W1, const float* __restrict__ as1, const float* __restrict__ ad1,
        float* __restrict__ xh2, float* __restrict__ als2, float* __restrict__ ald2,
        const float* __restrict__ x,
        const float* __restrict__ kW, const float* __restrict__ kb, float* __restrict__ kacc,
        const float* __restrict__ lpW, const float* __restrict__ lpb,
        const float* __restrict__ poolw, float* __restrict__ macc){
  __shared__ Smem sm;
  int t = threadIdx.x;
  if (blockIdx.x >= 512){
    kde_phase<0>(sm, nullptr, nullptr, x, blockIdx.x - 256, kW, kb, kacc, lpW, lpb, poolw, macc);
    return;
  }
  int sub = t >> 7, tl = t & 127;
  int d = blockIdx.x*4 + sub;
  float acc = gather_core(sm, d, sub, tl, csr, deg, als_in, ald_in, xh_in, bias);
  sm.xw.rows[sub][tl] = fmaxf(acc, 0.f);   // post-relu: input to both kde1 and xw1
  __syncthreads();
  write_transposed(sm, t, blockIdx.x*4, c1v, c1s);
  xw_emit(sm, sub, tl, d, W1, as1, ad1, xh2, als2, ald2);
}

// ======= L1: kde1 on c1 planes (bids 0..511) | gather1 -> cur2 planes (bids 512..1023) ======
__global__ __launch_bounds__(512) void k_L1(const float* __restrict__ c1v, const float* __restrict__ c1s,
        const float* __restrict__ kW, const float* __restrict__ kb, float* __restrict__ kacc,
        const float* __restrict__ lpW, const float* __restrict__ lpb,
        const float* __restrict__ poolw, float* __restrict__ macc,
        const int* __restrict__ csr, const int* __restrict__ deg,
        const float* __restrict__ als2, const float* __restrict__ ald2,
        const float* __restrict__ xh2, const float* __restrict__ bias,
        float* __restrict__ c2v, float* __restrict__ c2s){
  __shared__ Smem sm;
  int t = threadIdx.x;
  if (blockIdx.x < 512){
    kde_phase<1>(sm, c1v, c1s, nullptr, blockIdx.x, kW, kb, kacc, lpW, lpb, poolw, macc);
  } else {
    int b2 = blockIdx.x - 512;
    int sub = t >> 7, tl = t & 127;
    int d = b2*4 + sub;
    float acc = gather_core(sm, d, sub, tl, csr, deg, als2, ald2, xh2, bias);
    sm.xw.rows[sub][tl] = acc;             // no relu on last layer
    __syncthreads();
    write_transposed(sm, t, b2*4, c2v, c2s);
  }
}

// ================= L2: kde2 on c2 planes =================
__global__ __launch_bounds__(512) void k_L2(const float* __restrict__ c2v, const float* __restrict__ c2s,
        const float* __restrict__ kW, const float* __restrict__ kb, float* __restrict__ kacc,
        const float* __restrict__ lpW, const float* __restrict__ lpb,
        const float* __restrict__ poolw, float* __restrict__ macc){
  __shared__ Smem sm;
  kde_phase<1>(sm, c2v, c2s, nullptr, blockIdx.x, kW, kb, kacc, lpW, lpb, poolw, macc);
}

// ================= final: reduce dense partials [3][128 d][128 (g,o)] =================
__global__ __launch_bounds__(384) void k_final(const float* __restrict__ mpart, const float* __restrict__ kpart,
                        const float* __restrict__ beta, const float* __restrict__ h0,
                        float* __restrict__ out){
  int t = threadIdx.x;   // 384: l = t>>7, (g,o) = t&127
  __shared__ float sdm[384];
  int l = t >> 7, tt = t & 127;
  const float* mrow = mpart + (size_t)l*16384 + tt;
  const float* krow = kpart + (size_t)l*16384 + tt;
  float s = 0.f;
  #pragma unroll 8
  for (int d2=0; d2<128; ++d2) s += mrow[(size_t)d2*128] + krow[(size_t)d2*128];
  sdm[t] = s;
  __syncthreads();
  if (t < 128){
    int g = t >> 5, o = t & 31;
    float s3 = (sdm[t] + sdm[t+128] + sdm[t+256]) * (1.f/3.f) * beta[o];
    #pragma unroll
    for (int m=16; m>0; m>>=1) s3 += __shfl_xor(s3, m, 32);
    if (o == 0) out[g] = s3 + h0[0];
  }
}

extern "C" void kernel_launch(void* const* d_in, const int* in_sizes, int n_in,
                              void* d_out, int out_size, void* d_ws, size_t ws_size,
                              hipStream_t stream) {
  (void)in_sizes; (void)n_in; (void)out_size; (void)ws_size;
  const float* x    = (const float*)d_in[0];
  const int*   ei   = (const int*)d_in[1];
  const int*   srcp = ei;
  const int*   dstp = ei + EE;
  const float* W[2]   = {(const float*)d_in[3], (const float*)d_in[7]};
  const float* As[2]  = {(const float*)d_in[4], (const float*)d_in[8]};
  const float* Ad[2]  = {(const float*)d_in[5], (const float*)d_in[9]};
  const float* Bi[2]  = {(const float*)d_in[6], (const float*)d_in[10]};
  const float* lpW[3] = {(const float*)d_in[11], (const float*)d_in[13], (const float*)d_in[15]};
  const float* lpb[3] = {(const float*)d_in[12], (const float*)d_in[14], (const float*)d_in[16]};
  const float* kW[3]  = {(const float*)d_in[17], (const float*)d_in[19], (const float*)d_in[21]};
  const float* kb[3]  = {(const float*)d_in[18], (const float*)d_in[20], (const float*)d_in[22]};
  const float* poolw  = (const float*)d_in[23];
  const float* beta   = (const float*)d_in[24];
  const float* h0     = (const float*)d_in[25];
  float* out = (float*)d_out;

  // workspace layout (floats unless noted); c1/c2 are (v, v^2) plane pairs [128][2048]
  float* ws = (float*)d_ws;
  float* c1v   = ws;                   // 262144
  float* c1s   = c1v + 262144;         // 262144
  float* c2v   = c1s + 262144;         // 262144
  float* c2s   = c2v + 262144;         // 262144
  float* xh    = c2s + 262144;         // 262144 (layer 0)
  float* xh2   = xh + 262144;          // 262144 (layer 1)
  float* als   = xh2 + 262144;         // 8192
  float* ald   = als + 8192;           // 8192
  float* als2  = ald + 8192;           // 8192
  float* ald2  = als2 + 8192;          // 8192
  float* mpart = ald2 + 8192;          // 3*128*128 = 49152 (dense, no init needed)
  float* kpart = mpart + 49152;        // 49152
  int*   deg   = (int*)(kpart + 49152);// 2048
  int*   csr   = deg + 2048;           // 2048*160

  k_L0<<<768, 512, 0, stream>>>(x, kW[0], kb[0], kpart, lpW[0], lpb[0], poolw, mpart,
                                W[0], As[0], Ad[0], xh, als, ald,
                                srcp, dstp, deg, csr);
  k_G0<<<768, 512, 0, stream>>>(csr, deg, als, ald, xh, Bi[0], c1v, c1s,
                                W[1], As[1], Ad[1], xh2, als2, ald2,
                                x, kW[0], kb[0], kpart, lpW[0], lpb[0], poolw, mpart);
  k_L1<<<1024, 512, 0, stream>>>(c1v, c1s, kW[1], kb[1], kpart+16384, lpW[1], lpb[1], poolw, mpart+16384,
                                 csr, deg, als2, ald2, xh2, Bi[1], c2v, c2s);
  k_L2<<<512, 512, 0, stream>>>(c2v, c2s, kW[2], kb[2], kpart+32768, lpW[2], lpb[2], poolw, mpart+32768);
  k_final<<<1, 384, 0, stream>>>(mpart, kpart, beta, h0, out);
}